// Round 8
// baseline (280.452 us; speedup 1.0000x reference)
//
#include <hip/hip_runtime.h>

#define B 4
#define N 512
#define HID 64
#define HEADS 4
#define DH 16
#define SCALE 0.25f
#define NEG (-1e9f)
#define LN_EPS 1e-5f

#define REPS 32   // calibration: attn work replicated; rep>0 writes to scratch

constexpr int ROWS = B * N;                       // 2048
constexpr size_t OFF_ST  = 0;
constexpr size_t OFF_Q   = (size_t)ROWS * HID;    // 131072 floats
constexpr size_t OFF_K   = 2 * OFF_Q;
constexpr size_t OFF_V   = 3 * OFF_Q;
constexpr size_t OFF_MSG = 4 * OFF_Q;
constexpr size_t OFF_SCR = 5 * OFF_Q;             // dead scratch for rep>0

// ---------------------------------------------------------------------------
// Kernel A: fused projections (identical to R4 best).
// ---------------------------------------------------------------------------
__global__ __launch_bounds__(256) void proj_kernel(
    const float* __restrict__ x,
    const float* __restrict__ W1w, const float* __restrict__ W1b,
    const float* __restrict__ W2w, const float* __restrict__ W2b,
    const float* __restrict__ W3w, const float* __restrict__ W3b,
    const float* __restrict__ W4w, const float* __restrict__ W4b,
    float* __restrict__ ws)
{
  __shared__ float xsT[64 * 8];      // [k][r]
  const int t = threadIdx.x;
  const int rows0 = blockIdx.x * 8;

  if (t < 128) {
    const float4 v = *(const float4*)&x[(size_t)rows0 * HID + t * 4];
    const int r = t >> 4;
    const int k0 = (t & 15) * 4;
    xsT[(k0 + 0) * 8 + r] = v.x;
    xsT[(k0 + 1) * 8 + r] = v.y;
    xsT[(k0 + 2) * 8 + r] = v.z;
    xsT[(k0 + 3) * 8 + r] = v.w;
  }
  __syncthreads();

  const int m = t >> 6;
  const int c = t & 63;
  const float* Ww; const float* Wb; size_t off;
  if      (m == 0) { Ww = W1w; Wb = W1b; off = OFF_ST; }
  else if (m == 1) { Ww = W3w; Wb = W3b; off = OFF_Q;  }
  else if (m == 2) { Ww = W4w; Wb = W4b; off = OFF_K;  }
  else             { Ww = W2w; Wb = W2b; off = OFF_V;  }

  float acc[8];
#pragma unroll
  for (int r = 0; r < 8; ++r) acc[r] = 0.f;

#pragma unroll 16
  for (int k = 0; k < 64; ++k) {
    const float w = Ww[(k << 6) + c];
    const float* xr = &xsT[k * 8];
    const float4 a0 = *(const float4*)(xr);
    const float4 a1 = *(const float4*)(xr + 4);
    acc[0] = fmaf(a0.x, w, acc[0]); acc[1] = fmaf(a0.y, w, acc[1]);
    acc[2] = fmaf(a0.z, w, acc[2]); acc[3] = fmaf(a0.w, w, acc[3]);
    acc[4] = fmaf(a1.x, w, acc[4]); acc[5] = fmaf(a1.y, w, acc[5]);
    acc[6] = fmaf(a1.z, w, acc[6]); acc[7] = fmaf(a1.w, w, acc[7]);
  }

  const float bias = Wb[c];
  const size_t base = off + (size_t)rows0 * HID + c;
#pragma unroll
  for (int r = 0; r < 8; ++r)
    ws[base + (size_t)r * HID] = acc[r] + bias;
}

// ---------------------------------------------------------------------------
// Kernel B: R4 attention, ×REPS replicated along grid.z for calibration.
// blockIdx.z = b*?  -> rep = z>>2 (0..REPS-1), b = z&3. rep>0 writes scratch.
// ---------------------------------------------------------------------------
__global__ __launch_bounds__(256, 2) void attn_kernel(
    const int*   __restrict__ adj,
    const float* __restrict__ efeat,
    const float* __restrict__ W5w, const float* __restrict__ W5b,
    float* __restrict__ ws)
{
  __shared__ float Ksh[N * 20];     // 40 KB
  __shared__ float Vsh[N * 20];     // 40 KB

  const int it = blockIdx.x, h = blockIdx.y;
  const int bz = blockIdx.z;
  const int b   = bz & 3;
  const int rep = bz >> 2;
  const int t = threadIdx.x;
  const int g  = t & 15;
  const int il = t >> 4;
  const int i  = it * 16 + il;

  const float* Qb = ws + OFF_Q;
  const float* Kb = ws + OFF_K;
  const float* Vb = ws + OFF_V;
  float* msg = ws + (rep ? OFF_SCR : OFF_MSG);

  {  // stage K,V head-slices into LDS
    const int jj = t >> 2;
    const int dq = (t & 3) << 2;
#pragma unroll
    for (int p = 0; p < 8; ++p) {
      const int j = jj + (p << 6);
      const size_t gb = ((size_t)(b * N + j)) * HID + h * DH + dq;
      *(float4*)&Ksh[j * 20 + dq] = *(const float4*)&Kb[gb];
      *(float4*)&Vsh[j * 20 + dq] = *(const float4*)&Vb[gb];
    }
  }

  // Q fragment + edge scalars
  const float* qrow = Qb + ((size_t)(b * N + i)) * HID + h * DH;
  const float4 q0 = *(const float4*)(qrow);
  const float4 q1 = *(const float4*)(qrow + 4);
  const float4 q2 = *(const float4*)(qrow + 8);
  const float4 q3 = *(const float4*)(qrow + 12);
  const float4 w50 = *(const float4*)&W5w[h * DH];
  const float4 w51 = *(const float4*)&W5w[h * DH + 4];
  const float4 w52 = *(const float4*)&W5w[h * DH + 8];
  const float4 w53 = *(const float4*)&W5w[h * DH + 12];
  const float4 b50 = *(const float4*)&W5b[h * DH];
  const float4 b51 = *(const float4*)&W5b[h * DH + 4];
  const float4 b52 = *(const float4*)&W5b[h * DH + 8];
  const float4 b53 = *(const float4*)&W5b[h * DH + 12];
  const float qw5 = q0.x*w50.x + q0.y*w50.y + q0.z*w50.z + q0.w*w50.w
                  + q1.x*w51.x + q1.y*w51.y + q1.z*w51.z + q1.w*w51.w
                  + q2.x*w52.x + q2.y*w52.y + q2.z*w52.z + q2.w*w52.w
                  + q3.x*w53.x + q3.y*w53.y + q3.z*w53.z + q3.w*w53.w;
  const float qb5 = q0.x*b50.x + q0.y*b50.y + q0.z*b50.z + q0.w*b50.w
                  + q1.x*b51.x + q1.y*b51.y + q1.z*b51.z + q1.w*b51.w
                  + q2.x*b52.x + q2.y*b52.y + q2.z*b52.z + q2.w*b52.w
                  + q3.x*b53.x + q3.y*b53.y + q3.z*b53.z + q3.w*b53.w;

  __syncthreads();

  const int*   adjRow = adj   + ((size_t)(b * N + i)) * N;
  const float* eRow   = efeat + ((size_t)(b * N + i)) * N;

  // ---- pass 1: 32 masked scores into registers ---------------------------
  float s[32];
#pragma unroll
  for (int jj = 0; jj < 32; ++jj) {
    const int j = g + (jj << 4);
    const int   a  = adjRow[j];
    const float ev = eRow[j];
    const float* kr = &Ksh[j * 20];
    const float4 k0 = *(const float4*)(kr);
    const float4 k1 = *(const float4*)(kr + 4);
    const float4 k2 = *(const float4*)(kr + 8);
    const float4 k3 = *(const float4*)(kr + 12);
    float sA = q0.x*k0.x, sB = q0.y*k0.y, sC = q0.z*k0.z, sD = q0.w*k0.w;
    sA = fmaf(q1.x,k1.x,sA); sB = fmaf(q1.y,k1.y,sB);
    sC = fmaf(q1.z,k1.z,sC); sD = fmaf(q1.w,k1.w,sD);
    sA = fmaf(q2.x,k2.x,sA); sB = fmaf(q2.y,k2.y,sB);
    sC = fmaf(q2.z,k2.z,sC); sD = fmaf(q2.w,k2.w,sD);
    sA = fmaf(q3.x,k3.x,sA); sB = fmaf(q3.y,k3.y,sB);
    sC = fmaf(q3.z,k3.z,sC); sD = fmaf(q3.w,k3.w,sD);
    const float sc = ((sA + sB) + (sC + sD) + ev * qw5 + qb5) * SCALE;
    s[jj] = (a == 0) ? NEG : sc;
  }

  // ---- row max: pairwise tree + 16-lane shfl -----------------------------
  float r16[16], r8[8], r4[4];
#pragma unroll
  for (int k = 0; k < 16; ++k) r16[k] = fmaxf(s[k], s[k + 16]);
#pragma unroll
  for (int k = 0; k < 8;  ++k) r8[k]  = fmaxf(r16[k], r16[k + 8]);
#pragma unroll
  for (int k = 0; k < 4;  ++k) r4[k]  = fmaxf(r8[k], r8[k + 4]);
  float M = fmaxf(fmaxf(r4[0], r4[1]), fmaxf(r4[2], r4[3]));
#pragma unroll
  for (int o = 1; o < 16; o <<= 1) M = fmaxf(M, __shfl_xor(M, o, 16));

  // ---- pass 2: independent exps + PV accumulation ------------------------
  float l0 = 0.f, l1 = 0.f, l2 = 0.f, l3 = 0.f;
  float acc[16];
#pragma unroll
  for (int d = 0; d < 16; ++d) acc[d] = 0.f;

#pragma unroll
  for (int jj = 0; jj < 32; ++jj) {
    const int j = g + (jj << 4);
    const float p = __expf(s[jj] - M);
    if      ((jj & 3) == 0) l0 += p;
    else if ((jj & 3) == 1) l1 += p;
    else if ((jj & 3) == 2) l2 += p;
    else                    l3 += p;
    const float* vr = &Vsh[j * 20];
    const float4 v0 = *(const float4*)(vr);
    const float4 v1 = *(const float4*)(vr + 4);
    const float4 v2 = *(const float4*)(vr + 8);
    const float4 v3 = *(const float4*)(vr + 12);
    acc[0]  = fmaf(p, v0.x, acc[0]);  acc[1]  = fmaf(p, v0.y, acc[1]);
    acc[2]  = fmaf(p, v0.z, acc[2]);  acc[3]  = fmaf(p, v0.w, acc[3]);
    acc[4]  = fmaf(p, v1.x, acc[4]);  acc[5]  = fmaf(p, v1.y, acc[5]);
    acc[6]  = fmaf(p, v1.z, acc[6]);  acc[7]  = fmaf(p, v1.w, acc[7]);
    acc[8]  = fmaf(p, v2.x, acc[8]);  acc[9]  = fmaf(p, v2.y, acc[9]);
    acc[10] = fmaf(p, v2.z, acc[10]); acc[11] = fmaf(p, v2.w, acc[11]);
    acc[12] = fmaf(p, v3.x, acc[12]); acc[13] = fmaf(p, v3.y, acc[13]);
    acc[14] = fmaf(p, v3.z, acc[14]); acc[15] = fmaf(p, v3.w, acc[15]);
  }

  float lw = (l0 + l1) + (l2 + l3);
#pragma unroll
  for (int o = 1; o < 16; o <<= 1) lw += __shfl_xor(lw, o, 16);

  // ---- transpose-reduce acc across the 16 g-threads via LDS --------------
  __syncthreads();
  float* P = Ksh;
  const int prow = (il * 16 + g) * 20;
  *(float4*)&P[prow +  0] = make_float4(acc[0],  acc[1],  acc[2],  acc[3]);
  *(float4*)&P[prow +  4] = make_float4(acc[4],  acc[5],  acc[6],  acc[7]);
  *(float4*)&P[prow +  8] = make_float4(acc[8],  acc[9],  acc[10], acc[11]);
  *(float4*)&P[prow + 12] = make_float4(acc[12], acc[13], acc[14], acc[15]);
  __syncthreads();

  float ssum = 0.f;
#pragma unroll
  for (int gp = 0; gp < 16; ++gp)
    ssum += P[(il * 16 + gp) * 20 + g];

  msg[((size_t)(b * N + i)) * HID + h * DH + g] = ssum * (1.0f / lw);
}

// ---------------------------------------------------------------------------
// Kernel C: out = LayerNorm(x + self_t + msg). One wave per row.
// ---------------------------------------------------------------------------
__global__ __launch_bounds__(256) void ln_kernel(
    const float* __restrict__ x, const float* __restrict__ ws,
    const float* __restrict__ gamma, const float* __restrict__ beta,
    float* __restrict__ out)
{
  const int t = threadIdx.x;
  const int lane = t & 63;
  const int row = blockIdx.x * 4 + (t >> 6);
  const size_t idx = (size_t)row * HID + lane;
  const float* ST  = ws + OFF_ST;
  const float* MSG = ws + OFF_MSG;

  const float v = x[idx] + ST[idx] + MSG[idx];
  float mu = v;
#pragma unroll
  for (int o = 1; o < 64; o <<= 1) mu += __shfl_xor(mu, o, 64);
  mu *= (1.0f / 64.0f);
  const float dv = v - mu;
  float var = dv * dv;
#pragma unroll
  for (int o = 1; o < 64; o <<= 1) var += __shfl_xor(var, o, 64);
  var *= (1.0f / 64.0f);
  out[idx] = dv * rsqrtf(var + LN_EPS) * gamma[lane] + beta[lane];
}

// ---------------------------------------------------------------------------
extern "C" void kernel_launch(void* const* d_in, const int* in_sizes, int n_in,
                              void* d_out, int out_size, void* d_ws, size_t ws_size,
                              hipStream_t stream)
{
  const float* x   = (const float*)d_in[0];
  const int*   adj = (const int*)d_in[1];
  const float* ef  = (const float*)d_in[2];
  const float* W1w = (const float*)d_in[3];
  const float* W1b = (const float*)d_in[4];
  const float* W2w = (const float*)d_in[5];
  const float* W2b = (const float*)d_in[6];
  const float* W3w = (const float*)d_in[7];
  const float* W3b = (const float*)d_in[8];
  const float* W4w = (const float*)d_in[9];
  const float* W4b = (const float*)d_in[10];
  const float* W5w = (const float*)d_in[11];
  const float* W5b = (const float*)d_in[12];
  const float* lng = (const float*)d_in[13];
  const float* lnb = (const float*)d_in[14];
  float* ws  = (float*)d_ws;
  float* out = (float*)d_out;

  proj_kernel<<<ROWS / 8, 256, 0, stream>>>(x, W1w, W1b, W2w, W2b, W3w, W3b, W4w, W4b, ws);
  attn_kernel<<<dim3(32, HEADS, B * REPS), 256, 0, stream>>>(adj, ef, W5w, W5b, ws);
  ln_kernel<<<ROWS / 4, 256, 0, stream>>>(x, ws, lng, lnb, out);
}

// Round 9
// 28.686 us; speedup vs baseline: 9.7766x; 9.7766x over previous
//
#include <hip/hip_runtime.h>

#define B 4
#define N 512
#define HID 64
#define HEADS 4
#define DH 16
#define SCALE 0.25f
#define NEG (-1e9f)
#define LN_EPS 1e-5f

constexpr int ROWS = B * N;                       // 2048
constexpr size_t OFF_ST  = 0;
constexpr size_t OFF_Q   = (size_t)ROWS * HID;    // 131072 floats
constexpr size_t OFF_K   = 2 * OFF_Q;
constexpr size_t OFF_V   = 3 * OFF_Q;
constexpr size_t OFF_MSG = 4 * OFF_Q;             // total ws use: 2.62 MB

// ---------------------------------------------------------------------------
// Kernel A: fused projections. ST=x@W1+b1, Q=x@W3+b3, K=x@W4+b4, V=x@W2+b2
// ---------------------------------------------------------------------------
__global__ __launch_bounds__(256) void proj_kernel(
    const float* __restrict__ x,
    const float* __restrict__ W1w, const float* __restrict__ W1b,
    const float* __restrict__ W2w, const float* __restrict__ W2b,
    const float* __restrict__ W3w, const float* __restrict__ W3b,
    const float* __restrict__ W4w, const float* __restrict__ W4b,
    float* __restrict__ ws)
{
  __shared__ float xsT[64 * 8];      // [k][r]
  const int t = threadIdx.x;
  const int rows0 = blockIdx.x * 8;

  if (t < 128) {
    const float4 v = *(const float4*)&x[(size_t)rows0 * HID + t * 4];
    const int r = t >> 4;
    const int k0 = (t & 15) * 4;
    xsT[(k0 + 0) * 8 + r] = v.x;
    xsT[(k0 + 1) * 8 + r] = v.y;
    xsT[(k0 + 2) * 8 + r] = v.z;
    xsT[(k0 + 3) * 8 + r] = v.w;
  }
  __syncthreads();

  const int m = t >> 6;
  const int c = t & 63;
  const float* Ww; const float* Wb; size_t off;
  if      (m == 0) { Ww = W1w; Wb = W1b; off = OFF_ST; }
  else if (m == 1) { Ww = W3w; Wb = W3b; off = OFF_Q;  }
  else if (m == 2) { Ww = W4w; Wb = W4b; off = OFF_K;  }
  else             { Ww = W2w; Wb = W2b; off = OFF_V;  }

  float acc[8];
#pragma unroll
  for (int r = 0; r < 8; ++r) acc[r] = 0.f;

#pragma unroll 16
  for (int k = 0; k < 64; ++k) {
    const float w = Ww[(k << 6) + c];
    const float* xr = &xsT[k * 8];
    const float4 a0 = *(const float4*)(xr);
    const float4 a1 = *(const float4*)(xr + 4);
    acc[0] = fmaf(a0.x, w, acc[0]); acc[1] = fmaf(a0.y, w, acc[1]);
    acc[2] = fmaf(a0.z, w, acc[2]); acc[3] = fmaf(a0.w, w, acc[3]);
    acc[4] = fmaf(a1.x, w, acc[4]); acc[5] = fmaf(a1.y, w, acc[5]);
    acc[6] = fmaf(a1.z, w, acc[6]); acc[7] = fmaf(a1.w, w, acc[7]);
  }

  const float bias = Wb[c];
  const size_t base = off + (size_t)rows0 * HID + c;
#pragma unroll
  for (int r = 0; r < 8; ++r)
    ws[base + (size_t)r * HID] = acc[r] + bias;
}

// ---------------------------------------------------------------------------
// Kernel B: two-pass register softmax; K and V TIME-SHARE one 40KB LDS
// buffer (stage K -> pass1 -> barrier -> stage V -> pass2). 40KB -> 4 blk/CU.
// grid (32,4,4) x 256 thr; thread (il,g): row i=it*16+il, j=g+16*jj.
// ---------------------------------------------------------------------------
__global__ __launch_bounds__(256, 4) void attn_kernel(
    const int*   __restrict__ adj,
    const float* __restrict__ efeat,
    const float* __restrict__ W5w, const float* __restrict__ W5b,
    float* __restrict__ ws)
{
  __shared__ float KV[N * 20];      // 40 KB, stride-20 rows (K, then V, then P)

  const int it = blockIdx.x, h = blockIdx.y, b = blockIdx.z;
  const int t = threadIdx.x;
  const int g  = t & 15;
  const int il = t >> 4;
  const int i  = it * 16 + il;

  const float* Qb = ws + OFF_Q;
  const float* Kb = ws + OFF_K;
  const float* Vb = ws + OFF_V;
  float* msg = ws + OFF_MSG;

  const int sj = t >> 2;             // staging row group
  const int sd = (t & 3) << 2;       // staging dword quad

  {  // stage K head-slice into LDS
#pragma unroll
    for (int p = 0; p < 8; ++p) {
      const int j = sj + (p << 6);
      const size_t gb = ((size_t)(b * N + j)) * HID + h * DH + sd;
      *(float4*)&KV[j * 20 + sd] = *(const float4*)&Kb[gb];
    }
  }

  // Q fragment + edge scalars
  const float* qrow = Qb + ((size_t)(b * N + i)) * HID + h * DH;
  const float4 q0 = *(const float4*)(qrow);
  const float4 q1 = *(const float4*)(qrow + 4);
  const float4 q2 = *(const float4*)(qrow + 8);
  const float4 q3 = *(const float4*)(qrow + 12);
  const float4 w50 = *(const float4*)&W5w[h * DH];
  const float4 w51 = *(const float4*)&W5w[h * DH + 4];
  const float4 w52 = *(const float4*)&W5w[h * DH + 8];
  const float4 w53 = *(const float4*)&W5w[h * DH + 12];
  const float4 b50 = *(const float4*)&W5b[h * DH];
  const float4 b51 = *(const float4*)&W5b[h * DH + 4];
  const float4 b52 = *(const float4*)&W5b[h * DH + 8];
  const float4 b53 = *(const float4*)&W5b[h * DH + 12];
  const float qw5 = q0.x*w50.x + q0.y*w50.y + q0.z*w50.z + q0.w*w50.w
                  + q1.x*w51.x + q1.y*w51.y + q1.z*w51.z + q1.w*w51.w
                  + q2.x*w52.x + q2.y*w52.y + q2.z*w52.z + q2.w*w52.w
                  + q3.x*w53.x + q3.y*w53.y + q3.z*w53.z + q3.w*w53.w;
  const float qb5 = q0.x*b50.x + q0.y*b50.y + q0.z*b50.z + q0.w*b50.w
                  + q1.x*b51.x + q1.y*b51.y + q1.z*b51.z + q1.w*b51.w
                  + q2.x*b52.x + q2.y*b52.y + q2.z*b52.z + q2.w*b52.w
                  + q3.x*b53.x + q3.y*b53.y + q3.z*b53.z + q3.w*b53.w;

  __syncthreads();

  const int*   adjRow = adj   + ((size_t)(b * N + i)) * N;
  const float* eRow   = efeat + ((size_t)(b * N + i)) * N;

  // ---- pass 1: 32 masked scores into registers (K in LDS) ----------------
  float s[32];
#pragma unroll
  for (int jj = 0; jj < 32; ++jj) {
    const int j = g + (jj << 4);
    const int   a  = adjRow[j];
    const float ev = eRow[j];
    const float* kr = &KV[j * 20];
    const float4 k0 = *(const float4*)(kr);
    const float4 k1 = *(const float4*)(kr + 4);
    const float4 k2 = *(const float4*)(kr + 8);
    const float4 k3 = *(const float4*)(kr + 12);
    float sA = q0.x*k0.x, sB = q0.y*k0.y, sC = q0.z*k0.z, sD = q0.w*k0.w;
    sA = fmaf(q1.x,k1.x,sA); sB = fmaf(q1.y,k1.y,sB);
    sC = fmaf(q1.z,k1.z,sC); sD = fmaf(q1.w,k1.w,sD);
    sA = fmaf(q2.x,k2.x,sA); sB = fmaf(q2.y,k2.y,sB);
    sC = fmaf(q2.z,k2.z,sC); sD = fmaf(q2.w,k2.w,sD);
    sA = fmaf(q3.x,k3.x,sA); sB = fmaf(q3.y,k3.y,sB);
    sC = fmaf(q3.z,k3.z,sC); sD = fmaf(q3.w,k3.w,sD);
    const float sc = ((sA + sB) + (sC + sD) + ev * qw5 + qb5) * SCALE;
    s[jj] = (a == 0) ? NEG : sc;
  }

  // ---- row max: pairwise tree + 16-lane shfl -----------------------------
  float r16[16], r8[8], r4[4];
#pragma unroll
  for (int k = 0; k < 16; ++k) r16[k] = fmaxf(s[k], s[k + 16]);
#pragma unroll
  for (int k = 0; k < 8;  ++k) r8[k]  = fmaxf(r16[k], r16[k + 8]);
#pragma unroll
  for (int k = 0; k < 4;  ++k) r4[k]  = fmaxf(r8[k], r8[k + 4]);
  float M = fmaxf(fmaxf(r4[0], r4[1]), fmaxf(r4[2], r4[3]));
#pragma unroll
  for (int o = 1; o < 16; o <<= 1) M = fmaxf(M, __shfl_xor(M, o, 16));

  // ---- swap buffer contents: K -> V --------------------------------------
  __syncthreads();                   // all K reads done
  {
#pragma unroll
    for (int p = 0; p < 8; ++p) {
      const int j = sj + (p << 6);
      const size_t gb = ((size_t)(b * N + j)) * HID + h * DH + sd;
      *(float4*)&KV[j * 20 + sd] = *(const float4*)&Vb[gb];  // L2-hot
    }
  }
  __syncthreads();

  // ---- pass 2: independent exps + PV accumulation (V in LDS) -------------
  float l0 = 0.f, l1 = 0.f, l2 = 0.f, l3 = 0.f;
  float acc[16];
#pragma unroll
  for (int d = 0; d < 16; ++d) acc[d] = 0.f;

#pragma unroll
  for (int jj = 0; jj < 32; ++jj) {
    const int j = g + (jj << 4);
    const float p = __expf(s[jj] - M);
    if      ((jj & 3) == 0) l0 += p;
    else if ((jj & 3) == 1) l1 += p;
    else if ((jj & 3) == 2) l2 += p;
    else                    l3 += p;
    const float* vr = &KV[j * 20];
    const float4 v0 = *(const float4*)(vr);
    const float4 v1 = *(const float4*)(vr + 4);
    const float4 v2 = *(const float4*)(vr + 8);
    const float4 v3 = *(const float4*)(vr + 12);
    acc[0]  = fmaf(p, v0.x, acc[0]);  acc[1]  = fmaf(p, v0.y, acc[1]);
    acc[2]  = fmaf(p, v0.z, acc[2]);  acc[3]  = fmaf(p, v0.w, acc[3]);
    acc[4]  = fmaf(p, v1.x, acc[4]);  acc[5]  = fmaf(p, v1.y, acc[5]);
    acc[6]  = fmaf(p, v1.z, acc[6]);  acc[7]  = fmaf(p, v1.w, acc[7]);
    acc[8]  = fmaf(p, v2.x, acc[8]);  acc[9]  = fmaf(p, v2.y, acc[9]);
    acc[10] = fmaf(p, v2.z, acc[10]); acc[11] = fmaf(p, v2.w, acc[11]);
    acc[12] = fmaf(p, v3.x, acc[12]); acc[13] = fmaf(p, v3.y, acc[13]);
    acc[14] = fmaf(p, v3.z, acc[14]); acc[15] = fmaf(p, v3.w, acc[15]);
  }

  float lw = (l0 + l1) + (l2 + l3);
#pragma unroll
  for (int o = 1; o < 16; o <<= 1) lw += __shfl_xor(lw, o, 16);

  // ---- transpose-reduce acc across the 16 g-threads via LDS --------------
  __syncthreads();                   // all V reads done
  float* P = KV;                     // first 5120 floats
  const int prow = (il * 16 + g) * 20;
  *(float4*)&P[prow +  0] = make_float4(acc[0],  acc[1],  acc[2],  acc[3]);
  *(float4*)&P[prow +  4] = make_float4(acc[4],  acc[5],  acc[6],  acc[7]);
  *(float4*)&P[prow +  8] = make_float4(acc[8],  acc[9],  acc[10], acc[11]);
  *(float4*)&P[prow + 12] = make_float4(acc[12], acc[13], acc[14], acc[15]);
  __syncthreads();

  float ssum = 0.f;
#pragma unroll
  for (int gp = 0; gp < 16; ++gp)
    ssum += P[(il * 16 + gp) * 20 + g];

  msg[((size_t)(b * N + i)) * HID + h * DH + g] = ssum * (1.0f / lw);
}

// ---------------------------------------------------------------------------
// Kernel C: out = LayerNorm(x + self_t + msg). One wave per row.
// ---------------------------------------------------------------------------
__global__ __launch_bounds__(256) void ln_kernel(
    const float* __restrict__ x, const float* __restrict__ ws,
    const float* __restrict__ gamma, const float* __restrict__ beta,
    float* __restrict__ out)
{
  const int t = threadIdx.x;
  const int lane = t & 63;
  const int row = blockIdx.x * 4 + (t >> 6);
  const size_t idx = (size_t)row * HID + lane;
  const float* ST  = ws + OFF_ST;
  const float* MSG = ws + OFF_MSG;

  const float v = x[idx] + ST[idx] + MSG[idx];
  float mu = v;
#pragma unroll
  for (int o = 1; o < 64; o <<= 1) mu += __shfl_xor(mu, o, 64);
  mu *= (1.0f / 64.0f);
  const float dv = v - mu;
  float var = dv * dv;
#pragma unroll
  for (int o = 1; o < 64; o <<= 1) var += __shfl_xor(var, o, 64);
  var *= (1.0f / 64.0f);
  out[idx] = dv * rsqrtf(var + LN_EPS) * gamma[lane] + beta[lane];
}

// ---------------------------------------------------------------------------
extern "C" void kernel_launch(void* const* d_in, const int* in_sizes, int n_in,
                              void* d_out, int out_size, void* d_ws, size_t ws_size,
                              hipStream_t stream)
{
  const float* x   = (const float*)d_in[0];
  const int*   adj = (const int*)d_in[1];
  const float* ef  = (const float*)d_in[2];
  const float* W1w = (const float*)d_in[3];
  const float* W1b = (const float*)d_in[4];
  const float* W2w = (const float*)d_in[5];
  const float* W2b = (const float*)d_in[6];
  const float* W3w = (const float*)d_in[7];
  const float* W3b = (const float*)d_in[8];
  const float* W4w = (const float*)d_in[9];
  const float* W4b = (const float*)d_in[10];
  const float* W5w = (const float*)d_in[11];
  const float* W5b = (const float*)d_in[12];
  const float* lng = (const float*)d_in[13];
  const float* lnb = (const float*)d_in[14];
  float* ws  = (float*)d_ws;
  float* out = (float*)d_out;

  proj_kernel<<<ROWS / 8, 256, 0, stream>>>(x, W1w, W1b, W2w, W2b, W3w, W3b, W4w, W4b, ws);
  attn_kernel<<<dim3(32, HEADS, B), 256, 0, stream>>>(adj, ef, W5w, W5b, ws);
  ln_kernel<<<ROWS / 4, 256, 0, stream>>>(x, ws, lng, lnb, out);
}

// Round 10
// 23.157 us; speedup vs baseline: 12.1109x; 1.2388x over previous
//
#include <hip/hip_runtime.h>

#define B 4
#define N 512
#define HID 64
#define HEADS 4
#define DH 16
#define SCALE 0.25f
#define NEG (-1e9f)
#define LN_EPS 1e-5f

constexpr int ROWS = B * N;                       // 2048
constexpr size_t OFF_ST  = 0;
constexpr size_t OFF_Q   = (size_t)ROWS * HID;    // 131072 floats
constexpr size_t OFF_K   = 2 * OFF_Q;
constexpr size_t OFF_V   = 3 * OFF_Q;
constexpr size_t OFF_PART= 4 * OFF_Q;             // partials: [row][h][half][18]

// ---------------------------------------------------------------------------
// Kernel A: fused projections. ST=x@W1+b1, Q=x@W3+b3, K=x@W4+b4, V=x@W2+b2
// ---------------------------------------------------------------------------
__global__ __launch_bounds__(256) void proj_kernel(
    const float* __restrict__ x,
    const float* __restrict__ W1w, const float* __restrict__ W1b,
    const float* __restrict__ W2w, const float* __restrict__ W2b,
    const float* __restrict__ W3w, const float* __restrict__ W3b,
    const float* __restrict__ W4w, const float* __restrict__ W4b,
    float* __restrict__ ws)
{
  __shared__ float xsT[64 * 8];      // [k][r]
  const int t = threadIdx.x;
  const int rows0 = blockIdx.x * 8;

  if (t < 128) {
    const float4 v = *(const float4*)&x[(size_t)rows0 * HID + t * 4];
    const int r = t >> 4;
    const int k0 = (t & 15) * 4;
    xsT[(k0 + 0) * 8 + r] = v.x;
    xsT[(k0 + 1) * 8 + r] = v.y;
    xsT[(k0 + 2) * 8 + r] = v.z;
    xsT[(k0 + 3) * 8 + r] = v.w;
  }
  __syncthreads();

  const int m = t >> 6;
  const int c = t & 63;
  const float* Ww; const float* Wb; size_t off;
  if      (m == 0) { Ww = W1w; Wb = W1b; off = OFF_ST; }
  else if (m == 1) { Ww = W3w; Wb = W3b; off = OFF_Q;  }
  else if (m == 2) { Ww = W4w; Wb = W4b; off = OFF_K;  }
  else             { Ww = W2w; Wb = W2b; off = OFF_V;  }

  float acc[8];
#pragma unroll
  for (int r = 0; r < 8; ++r) acc[r] = 0.f;

#pragma unroll 16
  for (int k = 0; k < 64; ++k) {
    const float w = Ww[(k << 6) + c];
    const float* xr = &xsT[k * 8];
    const float4 a0 = *(const float4*)(xr);
    const float4 a1 = *(const float4*)(xr + 4);
    acc[0] = fmaf(a0.x, w, acc[0]); acc[1] = fmaf(a0.y, w, acc[1]);
    acc[2] = fmaf(a0.z, w, acc[2]); acc[3] = fmaf(a0.w, w, acc[3]);
    acc[4] = fmaf(a1.x, w, acc[4]); acc[5] = fmaf(a1.y, w, acc[5]);
    acc[6] = fmaf(a1.z, w, acc[6]); acc[7] = fmaf(a1.w, w, acc[7]);
  }

  const float bias = Wb[c];
  const size_t base = off + (size_t)rows0 * HID + c;
#pragma unroll
  for (int r = 0; r < 8; ++r)
    ws[base + (size_t)r * HID] = acc[r] + bias;
}

// ---------------------------------------------------------------------------
// Kernel B: split-K attention. Block = (i-tile, h, b, j-half); 1024 blocks.
// LDS = K half-slice [256][20] + V half-slice [256][20] = 40KB -> 4 blk/CU.
// Thread (il,g): row i = it*16+il, j = j0 + g + 16*jj, jj = 0..15.
// Emits unnormalized partials (acc[16], m, l) per (row, h, half).
// ---------------------------------------------------------------------------
__global__ __launch_bounds__(256, 4) void attn_kernel(
    const int*   __restrict__ adj,
    const float* __restrict__ efeat,
    const float* __restrict__ W5w, const float* __restrict__ W5b,
    float* __restrict__ ws)
{
  __shared__ float Ksh[256 * 20];   // 20 KB
  __shared__ float Vsh[256 * 20];   // 20 KB

  const int it = blockIdx.x, h = blockIdx.y;
  const int b    = blockIdx.z >> 1;
  const int half = blockIdx.z & 1;
  const int j0   = half << 8;        // 0 or 256
  const int t = threadIdx.x;
  const int g  = t & 15;
  const int il = t >> 4;
  const int i  = it * 16 + il;

  const float* Qb = ws + OFF_Q;
  const float* Kb = ws + OFF_K;
  const float* Vb = ws + OFF_V;
  float* part = ws + OFF_PART;

  {  // stage K,V half-slices into LDS (256 rows each)
    const int sj = t >> 2;
    const int dq = (t & 3) << 2;
#pragma unroll
    for (int p = 0; p < 4; ++p) {
      const int j = sj + (p << 6);   // 0..255 local
      const size_t gb = ((size_t)(b * N + j0 + j)) * HID + h * DH + dq;
      *(float4*)&Ksh[j * 20 + dq] = *(const float4*)&Kb[gb];
      *(float4*)&Vsh[j * 20 + dq] = *(const float4*)&Vb[gb];
    }
  }

  // Q fragment + edge scalars
  const float* qrow = Qb + ((size_t)(b * N + i)) * HID + h * DH;
  const float4 q0 = *(const float4*)(qrow);
  const float4 q1 = *(const float4*)(qrow + 4);
  const float4 q2 = *(const float4*)(qrow + 8);
  const float4 q3 = *(const float4*)(qrow + 12);
  const float4 w50 = *(const float4*)&W5w[h * DH];
  const float4 w51 = *(const float4*)&W5w[h * DH + 4];
  const float4 w52 = *(const float4*)&W5w[h * DH + 8];
  const float4 w53 = *(const float4*)&W5w[h * DH + 12];
  const float4 b50 = *(const float4*)&W5b[h * DH];
  const float4 b51 = *(const float4*)&W5b[h * DH + 4];
  const float4 b52 = *(const float4*)&W5b[h * DH + 8];
  const float4 b53 = *(const float4*)&W5b[h * DH + 12];
  const float qw5 = q0.x*w50.x + q0.y*w50.y + q0.z*w50.z + q0.w*w50.w
                  + q1.x*w51.x + q1.y*w51.y + q1.z*w51.z + q1.w*w51.w
                  + q2.x*w52.x + q2.y*w52.y + q2.z*w52.z + q2.w*w52.w
                  + q3.x*w53.x + q3.y*w53.y + q3.z*w53.z + q3.w*w53.w;
  const float qb5 = q0.x*b50.x + q0.y*b50.y + q0.z*b50.z + q0.w*b50.w
                  + q1.x*b51.x + q1.y*b51.y + q1.z*b51.z + q1.w*b51.w
                  + q2.x*b52.x + q2.y*b52.y + q2.z*b52.z + q2.w*b52.w
                  + q3.x*b53.x + q3.y*b53.y + q3.z*b53.z + q3.w*b53.w;

  __syncthreads();

  const int*   adjRow = adj   + ((size_t)(b * N + i)) * N + j0;
  const float* eRow   = efeat + ((size_t)(b * N + i)) * N + j0;

  // ---- pass 1: 16 masked scores into registers ---------------------------
  float s[16];
#pragma unroll
  for (int jj = 0; jj < 16; ++jj) {
    const int j = g + (jj << 4);     // local 0..255
    const int   a  = adjRow[j];
    const float ev = eRow[j];
    const float* kr = &Ksh[j * 20];
    const float4 k0 = *(const float4*)(kr);
    const float4 k1 = *(const float4*)(kr + 4);
    const float4 k2 = *(const float4*)(kr + 8);
    const float4 k3 = *(const float4*)(kr + 12);
    float sA = q0.x*k0.x, sB = q0.y*k0.y, sC = q0.z*k0.z, sD = q0.w*k0.w;
    sA = fmaf(q1.x,k1.x,sA); sB = fmaf(q1.y,k1.y,sB);
    sC = fmaf(q1.z,k1.z,sC); sD = fmaf(q1.w,k1.w,sD);
    sA = fmaf(q2.x,k2.x,sA); sB = fmaf(q2.y,k2.y,sB);
    sC = fmaf(q2.z,k2.z,sC); sD = fmaf(q2.w,k2.w,sD);
    sA = fmaf(q3.x,k3.x,sA); sB = fmaf(q3.y,k3.y,sB);
    sC = fmaf(q3.z,k3.z,sC); sD = fmaf(q3.w,k3.w,sD);
    const float sc = ((sA + sB) + (sC + sD) + ev * qw5 + qb5) * SCALE;
    s[jj] = (a == 0) ? NEG : sc;
  }

  // ---- half-row max: pairwise tree + 16-lane shfl ------------------------
  float r8[8], r4[4];
#pragma unroll
  for (int k = 0; k < 8; ++k) r8[k] = fmaxf(s[k], s[k + 8]);
#pragma unroll
  for (int k = 0; k < 4; ++k) r4[k] = fmaxf(r8[k], r8[k + 4]);
  float M = fmaxf(fmaxf(r4[0], r4[1]), fmaxf(r4[2], r4[3]));
#pragma unroll
  for (int o = 1; o < 16; o <<= 1) M = fmaxf(M, __shfl_xor(M, o, 16));

  // ---- pass 2: independent exps + PV accumulation ------------------------
  float l0 = 0.f, l1 = 0.f;
  float acc[16];
#pragma unroll
  for (int d = 0; d < 16; ++d) acc[d] = 0.f;

#pragma unroll
  for (int jj = 0; jj < 16; ++jj) {
    const int j = g + (jj << 4);
    const float p = __expf(s[jj] - M);
    if (jj & 1) l1 += p; else l0 += p;
    const float* vr = &Vsh[j * 20];
    const float4 v0 = *(const float4*)(vr);
    const float4 v1 = *(const float4*)(vr + 4);
    const float4 v2 = *(const float4*)(vr + 8);
    const float4 v3 = *(const float4*)(vr + 12);
    acc[0]  = fmaf(p, v0.x, acc[0]);  acc[1]  = fmaf(p, v0.y, acc[1]);
    acc[2]  = fmaf(p, v0.z, acc[2]);  acc[3]  = fmaf(p, v0.w, acc[3]);
    acc[4]  = fmaf(p, v1.x, acc[4]);  acc[5]  = fmaf(p, v1.y, acc[5]);
    acc[6]  = fmaf(p, v1.z, acc[6]);  acc[7]  = fmaf(p, v1.w, acc[7]);
    acc[8]  = fmaf(p, v2.x, acc[8]);  acc[9]  = fmaf(p, v2.y, acc[9]);
    acc[10] = fmaf(p, v2.z, acc[10]); acc[11] = fmaf(p, v2.w, acc[11]);
    acc[12] = fmaf(p, v3.x, acc[12]); acc[13] = fmaf(p, v3.y, acc[13]);
    acc[14] = fmaf(p, v3.z, acc[14]); acc[15] = fmaf(p, v3.w, acc[15]);
  }

  float lw = l0 + l1;
#pragma unroll
  for (int o = 1; o < 16; o <<= 1) lw += __shfl_xor(lw, o, 16);

  // ---- transpose-reduce acc across the 16 g-threads via LDS --------------
  __syncthreads();
  float* P = Ksh;                    // 256x20 f32 = exactly Ksh
  const int prow = (il * 16 + g) * 20;
  *(float4*)&P[prow +  0] = make_float4(acc[0],  acc[1],  acc[2],  acc[3]);
  *(float4*)&P[prow +  4] = make_float4(acc[4],  acc[5],  acc[6],  acc[7]);
  *(float4*)&P[prow +  8] = make_float4(acc[8],  acc[9],  acc[10], acc[11]);
  *(float4*)&P[prow + 12] = make_float4(acc[12], acc[13], acc[14], acc[15]);
  __syncthreads();

  float ssum = 0.f;
#pragma unroll
  for (int gp = 0; gp < 16; ++gp)
    ssum += P[(il * 16 + gp) * 20 + g];

  // ---- store unnormalized partial: [row][h][half][18] --------------------
  float* rec = part + ((((size_t)(b * N + i)) * HEADS + h) * 2 + half) * 18;
  rec[g] = ssum;
  if (g == 0) { rec[16] = M; rec[17] = lw; }
}

// ---------------------------------------------------------------------------
// Kernel C: merge j-half partials + residual + LayerNorm. One wave per row.
// Lane l: head h = l>>4, dim d = l&15 (matches HID layout h*16+d).
// ---------------------------------------------------------------------------
__global__ __launch_bounds__(256) void ln_kernel(
    const float* __restrict__ x, const float* __restrict__ ws,
    const float* __restrict__ gamma, const float* __restrict__ beta,
    float* __restrict__ out)
{
  const int t = threadIdx.x;
  const int lane = t & 63;
  const int row = blockIdx.x * 4 + (t >> 6);
  const size_t idx = (size_t)row * HID + lane;
  const float* ST   = ws + OFF_ST;
  const float* part = ws + OFF_PART;

  const int h = lane >> 4;
  const int d = lane & 15;
  const float* rec0 = part + (((size_t)row * HEADS + h) * 2 + 0) * 18;
  const float* rec1 = rec0 + 18;
  const float a0 = rec0[d], m0 = rec0[16], e0 = rec0[17];
  const float a1 = rec1[d], m1 = rec1[16], e1 = rec1[17];
  const float M  = fmaxf(m0, m1);
  const float w0 = __expf(m0 - M), w1 = __expf(m1 - M);
  const float msg = (a0 * w0 + a1 * w1) / (e0 * w0 + e1 * w1);

  const float v = x[idx] + ST[idx] + msg;
  float mu = v;
#pragma unroll
  for (int o = 1; o < 64; o <<= 1) mu += __shfl_xor(mu, o, 64);
  mu *= (1.0f / 64.0f);
  const float dv = v - mu;
  float var = dv * dv;
#pragma unroll
  for (int o = 1; o < 64; o <<= 1) var += __shfl_xor(var, o, 64);
  var *= (1.0f / 64.0f);
  out[idx] = dv * rsqrtf(var + LN_EPS) * gamma[lane] + beta[lane];
}

// ---------------------------------------------------------------------------
extern "C" void kernel_launch(void* const* d_in, const int* in_sizes, int n_in,
                              void* d_out, int out_size, void* d_ws, size_t ws_size,
                              hipStream_t stream)
{
  const float* x   = (const float*)d_in[0];
  const int*   adj = (const int*)d_in[1];
  const float* ef  = (const float*)d_in[2];
  const float* W1w = (const float*)d_in[3];
  const float* W1b = (const float*)d_in[4];
  const float* W2w = (const float*)d_in[5];
  const float* W2b = (const float*)d_in[6];
  const float* W3w = (const float*)d_in[7];
  const float* W3b = (const float*)d_in[8];
  const float* W4w = (const float*)d_in[9];
  const float* W4b = (const float*)d_in[10];
  const float* W5w = (const float*)d_in[11];
  const float* W5b = (const float*)d_in[12];
  const float* lng = (const float*)d_in[13];
  const float* lnb = (const float*)d_in[14];
  float* ws  = (float*)d_ws;
  float* out = (float*)d_out;

  proj_kernel<<<ROWS / 8, 256, 0, stream>>>(x, W1w, W1b, W2w, W2b, W3w, W3b, W4w, W4b, ws);
  attn_kernel<<<dim3(32, HEADS, B * 2), 256, 0, stream>>>(adj, ef, W5w, W5b, ws);
  ln_kernel<<<ROWS / 4, 256, 0, stream>>>(x, ws, lng, lnb, out);
}

// Round 11
// 23.039 us; speedup vs baseline: 12.1730x; 1.0051x over previous
//
#include <hip/hip_runtime.h>

#define B 4
#define N 512
#define HID 64
#define HEADS 4
#define DH 16
#define SCALE 0.25f
#define NEG (-1e9f)
#define LN_EPS 1e-5f

constexpr int ROWS = B * N;                       // 2048
constexpr size_t OFF_ST  = 0;
constexpr size_t OFF_Q   = (size_t)ROWS * HID;    // 131072 floats
constexpr size_t OFF_K   = 2 * OFF_Q;
constexpr size_t OFF_V   = 3 * OFF_Q;
constexpr size_t OFF_PART= 4 * OFF_Q;             // partials: [row][h][half][18]

// ---------------------------------------------------------------------------
// Kernel A: fused projections, 512 blocks x 4 rows (2 blocks/CU).
// ---------------------------------------------------------------------------
__global__ __launch_bounds__(256) void proj_kernel(
    const float* __restrict__ x,
    const float* __restrict__ W1w, const float* __restrict__ W1b,
    const float* __restrict__ W2w, const float* __restrict__ W2b,
    const float* __restrict__ W3w, const float* __restrict__ W3b,
    const float* __restrict__ W4w, const float* __restrict__ W4b,
    float* __restrict__ ws)
{
  __shared__ float xsT[64 * 4];      // [k][r], 4 rows
  const int t = threadIdx.x;
  const int rows0 = blockIdx.x * 4;

  if (t < 64) {
    const float4 v = *(const float4*)&x[(size_t)rows0 * HID + t * 4];
    const int r = t >> 4;            // row 0..3
    const int k0 = (t & 15) * 4;     // col 0..60
    xsT[(k0 + 0) * 4 + r] = v.x;
    xsT[(k0 + 1) * 4 + r] = v.y;
    xsT[(k0 + 2) * 4 + r] = v.z;
    xsT[(k0 + 3) * 4 + r] = v.w;
  }
  __syncthreads();

  const int m = t >> 6;              // one W matrix per wave
  const int c = t & 63;
  const float* Ww; const float* Wb; size_t off;
  if      (m == 0) { Ww = W1w; Wb = W1b; off = OFF_ST; }
  else if (m == 1) { Ww = W3w; Wb = W3b; off = OFF_Q;  }
  else if (m == 2) { Ww = W4w; Wb = W4b; off = OFF_K;  }
  else             { Ww = W2w; Wb = W2b; off = OFF_V;  }

  float acc[4];
#pragma unroll
  for (int r = 0; r < 4; ++r) acc[r] = 0.f;

#pragma unroll 16
  for (int k = 0; k < 64; ++k) {
    const float w = Ww[(k << 6) + c];              // coalesced per wave
    const float4 a0 = *(const float4*)&xsT[k * 4]; // wave-uniform -> broadcast
    acc[0] = fmaf(a0.x, w, acc[0]); acc[1] = fmaf(a0.y, w, acc[1]);
    acc[2] = fmaf(a0.z, w, acc[2]); acc[3] = fmaf(a0.w, w, acc[3]);
  }

  const float bias = Wb[c];
  const size_t base = off + (size_t)rows0 * HID + c;
#pragma unroll
  for (int r = 0; r < 4; ++r)
    ws[base + (size_t)r * HID] = acc[r] + bias;
}

// ---------------------------------------------------------------------------
// Kernel B: split-K attention, vectorized adj/ef loads.
// Block = (i-tile, h, b, j-half); 1024 blocks, 40KB LDS -> 4 blk/CU.
// Thread (il,g): row i = it*16+il; owns j_local = 4g + 64q + r (q,r in 0..3)
// -> adj/ef read as int4/float4 (coalesced 256B per lane-group).
// K/V stored at permuted LDS row sigma(j) = (j&3)*64 + (j>>2), so inner-loop
// lane stride stays 20 floats (<=2-way bank alias = free).
// ---------------------------------------------------------------------------
__global__ __launch_bounds__(256, 4) void attn_kernel(
    const int*   __restrict__ adj,
    const float* __restrict__ efeat,
    const float* __restrict__ W5w, const float* __restrict__ W5b,
    float* __restrict__ ws)
{
  __shared__ float Ksh[256 * 20];   // 20 KB
  __shared__ float Vsh[256 * 20];   // 20 KB

  const int it = blockIdx.x, h = blockIdx.y;
  const int b    = blockIdx.z >> 1;
  const int half = blockIdx.z & 1;
  const int j0   = half << 8;        // 0 or 256
  const int t = threadIdx.x;
  const int g  = t & 15;
  const int il = t >> 4;
  const int i  = it * 16 + il;

  const float* Qb = ws + OFF_Q;
  const float* Kb = ws + OFF_K;
  const float* Vb = ws + OFF_V;
  float* part = ws + OFF_PART;

  // ---- early vector loads: adj (int4) + efeat (float4), 4 each -----------
  const int*   adjRow = adj   + ((size_t)(b * N + i)) * N + j0;
  const float* eRow   = efeat + ((size_t)(b * N + i)) * N + j0;
  int4   av0 = *(const int4*)  &adjRow[4 * g];
  int4   av1 = *(const int4*)  &adjRow[4 * g + 64];
  int4   av2 = *(const int4*)  &adjRow[4 * g + 128];
  int4   av3 = *(const int4*)  &adjRow[4 * g + 192];
  float4 ev0 = *(const float4*)&eRow  [4 * g];
  float4 ev1 = *(const float4*)&eRow  [4 * g + 64];
  float4 ev2 = *(const float4*)&eRow  [4 * g + 128];
  float4 ev3 = *(const float4*)&eRow  [4 * g + 192];

  {  // stage K,V half-slices into LDS at sigma-permuted rows
    const int sj = t >> 2;
    const int dq = (t & 3) << 2;
#pragma unroll
    for (int p = 0; p < 4; ++p) {
      const int j  = sj + (p << 6);                 // 0..255 local
      const int sr = ((j & 3) << 6) | (j >> 2);     // sigma(j)
      const size_t gb = ((size_t)(b * N + j0 + j)) * HID + h * DH + dq;
      *(float4*)&Ksh[sr * 20 + dq] = *(const float4*)&Kb[gb];
      *(float4*)&Vsh[sr * 20 + dq] = *(const float4*)&Vb[gb];
    }
  }

  // Q fragment + edge scalars
  const float* qrow = Qb + ((size_t)(b * N + i)) * HID + h * DH;
  const float4 q0 = *(const float4*)(qrow);
  const float4 q1 = *(const float4*)(qrow + 4);
  const float4 q2 = *(const float4*)(qrow + 8);
  const float4 q3 = *(const float4*)(qrow + 12);
  const float4 w50 = *(const float4*)&W5w[h * DH];
  const float4 w51 = *(const float4*)&W5w[h * DH + 4];
  const float4 w52 = *(const float4*)&W5w[h * DH + 8];
  const float4 w53 = *(const float4*)&W5w[h * DH + 12];
  const float4 b50 = *(const float4*)&W5b[h * DH];
  const float4 b51 = *(const float4*)&W5b[h * DH + 4];
  const float4 b52 = *(const float4*)&W5b[h * DH + 8];
  const float4 b53 = *(const float4*)&W5b[h * DH + 12];
  const float qw5 = q0.x*w50.x + q0.y*w50.y + q0.z*w50.z + q0.w*w50.w
                  + q1.x*w51.x + q1.y*w51.y + q1.z*w51.z + q1.w*w51.w
                  + q2.x*w52.x + q2.y*w52.y + q2.z*w52.z + q2.w*w52.w
                  + q3.x*w53.x + q3.y*w53.y + q3.z*w53.z + q3.w*w53.w;
  const float qb5 = q0.x*b50.x + q0.y*b50.y + q0.z*b50.z + q0.w*b50.w
                  + q1.x*b51.x + q1.y*b51.y + q1.z*b51.z + q1.w*b51.w
                  + q2.x*b52.x + q2.y*b52.y + q2.z*b52.z + q2.w*b52.w
                  + q3.x*b53.x + q3.y*b53.y + q3.z*b53.z + q3.w*b53.w;

  __syncthreads();

  // ---- pass 1: 16 masked scores into registers ---------------------------
  float s[16];
#pragma unroll
  for (int q = 0; q < 4; ++q) {
#pragma unroll
    for (int r = 0; r < 4; ++r) {
      const int a    = (r == 0) ? (q==0?av0.x:q==1?av1.x:q==2?av2.x:av3.x)
                     : (r == 1) ? (q==0?av0.y:q==1?av1.y:q==2?av2.y:av3.y)
                     : (r == 2) ? (q==0?av0.z:q==1?av1.z:q==2?av2.z:av3.z)
                                : (q==0?av0.w:q==1?av1.w:q==2?av2.w:av3.w);
      const float ev = (r == 0) ? (q==0?ev0.x:q==1?ev1.x:q==2?ev2.x:ev3.x)
                     : (r == 1) ? (q==0?ev0.y:q==1?ev1.y:q==2?ev2.y:ev3.y)
                     : (r == 2) ? (q==0?ev0.z:q==1?ev1.z:q==2?ev2.z:ev3.z)
                                : (q==0?ev0.w:q==1?ev1.w:q==2?ev2.w:ev3.w);
      const int sr = (r << 6) | (g + (q << 4));     // sigma(4g+64q+r)
      const float* kr = &Ksh[sr * 20];
      const float4 k0 = *(const float4*)(kr);
      const float4 k1 = *(const float4*)(kr + 4);
      const float4 k2 = *(const float4*)(kr + 8);
      const float4 k3 = *(const float4*)(kr + 12);
      float sA = q0.x*k0.x, sB = q0.y*k0.y, sC = q0.z*k0.z, sD = q0.w*k0.w;
      sA = fmaf(q1.x,k1.x,sA); sB = fmaf(q1.y,k1.y,sB);
      sC = fmaf(q1.z,k1.z,sC); sD = fmaf(q1.w,k1.w,sD);
      sA = fmaf(q2.x,k2.x,sA); sB = fmaf(q2.y,k2.y,sB);
      sC = fmaf(q2.z,k2.z,sC); sD = fmaf(q2.w,k2.w,sD);
      sA = fmaf(q3.x,k3.x,sA); sB = fmaf(q3.y,k3.y,sB);
      sC = fmaf(q3.z,k3.z,sC); sD = fmaf(q3.w,k3.w,sD);
      const float sc = ((sA + sB) + (sC + sD) + ev * qw5 + qb5) * SCALE;
      s[(q << 2) | r] = (a == 0) ? NEG : sc;
    }
  }

  // ---- half-row max: pairwise tree + 16-lane shfl ------------------------
  float r8[8], r4[4];
#pragma unroll
  for (int k = 0; k < 8; ++k) r8[k] = fmaxf(s[k], s[k + 8]);
#pragma unroll
  for (int k = 0; k < 4; ++k) r4[k] = fmaxf(r8[k], r8[k + 4]);
  float M = fmaxf(fmaxf(r4[0], r4[1]), fmaxf(r4[2], r4[3]));
#pragma unroll
  for (int o = 1; o < 16; o <<= 1) M = fmaxf(M, __shfl_xor(M, o, 16));

  // ---- pass 2: independent exps + PV accumulation ------------------------
  float l0 = 0.f, l1 = 0.f;
  float acc[16];
#pragma unroll
  for (int d = 0; d < 16; ++d) acc[d] = 0.f;

#pragma unroll
  for (int q = 0; q < 4; ++q) {
#pragma unroll
    for (int r = 0; r < 4; ++r) {
      const int idx = (q << 2) | r;
      const float p = __expf(s[idx] - M);
      if (idx & 1) l1 += p; else l0 += p;
      const int sr = (r << 6) | (g + (q << 4));
      const float* vr = &Vsh[sr * 20];
      const float4 v0 = *(const float4*)(vr);
      const float4 v1 = *(const float4*)(vr + 4);
      const float4 v2 = *(const float4*)(vr + 8);
      const float4 v3 = *(const float4*)(vr + 12);
      acc[0]  = fmaf(p, v0.x, acc[0]);  acc[1]  = fmaf(p, v0.y, acc[1]);
      acc[2]  = fmaf(p, v0.z, acc[2]);  acc[3]  = fmaf(p, v0.w, acc[3]);
      acc[4]  = fmaf(p, v1.x, acc[4]);  acc[5]  = fmaf(p, v1.y, acc[5]);
      acc[6]  = fmaf(p, v1.z, acc[6]);  acc[7]  = fmaf(p, v1.w, acc[7]);
      acc[8]  = fmaf(p, v2.x, acc[8]);  acc[9]  = fmaf(p, v2.y, acc[9]);
      acc[10] = fmaf(p, v2.z, acc[10]); acc[11] = fmaf(p, v2.w, acc[11]);
      acc[12] = fmaf(p, v3.x, acc[12]); acc[13] = fmaf(p, v3.y, acc[13]);
      acc[14] = fmaf(p, v3.z, acc[14]); acc[15] = fmaf(p, v3.w, acc[15]);
    }
  }

  float lw = l0 + l1;
#pragma unroll
  for (int o = 1; o < 16; o <<= 1) lw += __shfl_xor(lw, o, 16);

  // ---- transpose-reduce acc across the 16 g-threads via LDS --------------
  __syncthreads();
  float* P = Ksh;                    // 256x20 scratch
  const int prow = (il * 16 + g) * 20;
  *(float4*)&P[prow +  0] = make_float4(acc[0],  acc[1],  acc[2],  acc[3]);
  *(float4*)&P[prow +  4] = make_float4(acc[4],  acc[5],  acc[6],  acc[7]);
  *(float4*)&P[prow +  8] = make_float4(acc[8],  acc[9],  acc[10], acc[11]);
  *(float4*)&P[prow + 12] = make_float4(acc[12], acc[13], acc[14], acc[15]);
  __syncthreads();

  float ssum = 0.f;
#pragma unroll
  for (int gp = 0; gp < 16; ++gp)
    ssum += P[(il * 16 + gp) * 20 + g];

  // ---- store unnormalized partial: [row][h][half][18] --------------------
  float* rec = part + ((((size_t)(b * N + i)) * HEADS + h) * 2 + half) * 18;
  rec[g] = ssum;
  if (g == 0) { rec[16] = M; rec[17] = lw; }
}

// ---------------------------------------------------------------------------
// Kernel C: merge j-half partials + residual + LayerNorm. One wave per row.
// ---------------------------------------------------------------------------
__global__ __launch_bounds__(256) void ln_kernel(
    const float* __restrict__ x, const float* __restrict__ ws,
    const float* __restrict__ gamma, const float* __restrict__ beta,
    float* __restrict__ out)
{
  const int t = threadIdx.x;
  const int lane = t & 63;
  const int row = blockIdx.x * 4 + (t >> 6);
  const size_t idx = (size_t)row * HID + lane;
  const float* ST   = ws + OFF_ST;
  const float* part = ws + OFF_PART;

  const int h = lane >> 4;
  const int d = lane & 15;
  const float* rec0 = part + (((size_t)row * HEADS + h) * 2 + 0) * 18;
  const float* rec1 = rec0 + 18;
  const float a0 = rec0[d], m0 = rec0[16], e0 = rec0[17];
  const float a1 = rec1[d], m1 = rec1[16], e1 = rec1[17];
  const float M  = fmaxf(m0, m1);
  const float w0 = __expf(m0 - M), w1 = __expf(m1 - M);
  const float msg = (a0 * w0 + a1 * w1) / (e0 * w0 + e1 * w1);

  const float v = x[idx] + ST[idx] + msg;
  float mu = v;
#pragma unroll
  for (int o = 1; o < 64; o <<= 1) mu += __shfl_xor(mu, o, 64);
  mu *= (1.0f / 64.0f);
  const float dv = v - mu;
  float var = dv * dv;
#pragma unroll
  for (int o = 1; o < 64; o <<= 1) var += __shfl_xor(var, o, 64);
  var *= (1.0f / 64.0f);
  out[idx] = dv * rsqrtf(var + LN_EPS) * gamma[lane] + beta[lane];
}

// ---------------------------------------------------------------------------
extern "C" void kernel_launch(void* const* d_in, const int* in_sizes, int n_in,
                              void* d_out, int out_size, void* d_ws, size_t ws_size,
                              hipStream_t stream)
{
  const float* x   = (const float*)d_in[0];
  const int*   adj = (const int*)d_in[1];
  const float* ef  = (const float*)d_in[2];
  const float* W1w = (const float*)d_in[3];
  const float* W1b = (const float*)d_in[4];
  const float* W2w = (const float*)d_in[5];
  const float* W2b = (const float*)d_in[6];
  const float* W3w = (const float*)d_in[7];
  const float* W3b = (const float*)d_in[8];
  const float* W4w = (const float*)d_in[9];
  const float* W4b = (const float*)d_in[10];
  const float* W5w = (const float*)d_in[11];
  const float* W5b = (const float*)d_in[12];
  const float* lng = (const float*)d_in[13];
  const float* lnb = (const float*)d_in[14];
  float* ws  = (float*)d_ws;
  float* out = (float*)d_out;

  proj_kernel<<<ROWS / 4, 256, 0, stream>>>(x, W1w, W1b, W2w, W2b, W3w, W3b, W4w, W4b, ws);
  attn_kernel<<<dim3(32, HEADS, B * 2), 256, 0, stream>>>(adj, ef, W5w, W5b, ws);
  ln_kernel<<<ROWS / 4, 256, 0, stream>>>(x, ws, lng, lnb, out);
}